// Round 1
// baseline (605.808 us; speedup 1.0000x reference)
//
#include <hip/hip_runtime.h>

typedef _Float16 f16;
typedef _Float16 f16x8 __attribute__((ext_vector_type(8)));
typedef float f32x4 __attribute__((ext_vector_type(4)));

#define D_ 1024
#define H_ 16
#define HD_ 64
#define B_ 2
#define S_ 2048
#define M_ 4096          // B_*S_
#define SCALE 0.125f
#define NEG_BIG -1e30f

__device__ __forceinline__ float red16_max(float v) {
#pragma unroll
  for (int m = 8; m >= 1; m >>= 1) v = fmaxf(v, __shfl_xor(v, m));
  return v;
}
__device__ __forceinline__ float red16_sum(float v) {
#pragma unroll
  for (int m = 8; m >= 1; m >>= 1) v += __shfl_xor(v, m);
  return v;
}

// ---------------- 128x128 GEMM tile body: C = A(MxK) * Bw(NxK)^T ----------------
// A is f32 or f16 (converted to f16 in staging); Bw is f32 weights (N x K, row-major).
template<typename TA>
__device__ __forceinline__ void gemm128(const TA* __restrict__ A, const float* __restrict__ Bw,
                                        int K, int bm, int bn, f32x4 acc[4][4])
{
  __shared__ f16 As[128][72];
  __shared__ f16 Bs[128][72];
  const int tid = threadIdx.x;
  const int lane = tid & 63, wid = tid >> 6;
  const int wr = wid >> 1, wc = wid & 1, g = lane >> 4, li = lane & 15;

#pragma unroll
  for (int m = 0; m < 4; ++m)
#pragma unroll
    for (int n = 0; n < 4; ++n)
      acc[m][n] = (f32x4){0.f, 0.f, 0.f, 0.f};

  for (int k0 = 0; k0 < K; k0 += 64) {
#pragma unroll
    for (int i = 0; i < 4; ++i) {
      int slot = tid + i * 256;
      int row = slot >> 3, ch = (slot & 7) * 8;
      f16x8 av;
      if constexpr (sizeof(TA) == 4) {
        const f32x4* p = (const f32x4*)((const float*)A + (size_t)(bm + row) * K + k0 + ch);
        f32x4 u0 = p[0], u1 = p[1];
#pragma unroll
        for (int j = 0; j < 4; ++j) { av[j] = (f16)u0[j]; av[j + 4] = (f16)u1[j]; }
      } else {
        av = *(const f16x8*)((const f16*)A + (size_t)(bm + row) * K + k0 + ch);
      }
      *(f16x8*)&As[row][ch] = av;
      const f32x4* pb = (const f32x4*)(Bw + (size_t)(bn + row) * K + k0 + ch);
      f32x4 v0 = pb[0], v1 = pb[1];
      f16x8 bv;
#pragma unroll
      for (int j = 0; j < 4; ++j) { bv[j] = (f16)v0[j]; bv[j + 4] = (f16)v1[j]; }
      *(f16x8*)&Bs[row][ch] = bv;
    }
    __syncthreads();
#pragma unroll
    for (int kk = 0; kk < 64; kk += 32) {
      f16x8 af[4], bf[4];
#pragma unroll
      for (int m = 0; m < 4; ++m) af[m] = *(const f16x8*)&As[wr * 64 + m * 16 + li][kk + g * 8];
#pragma unroll
      for (int n = 0; n < 4; ++n) bf[n] = *(const f16x8*)&Bs[wc * 64 + n * 16 + li][kk + g * 8];
#pragma unroll
      for (int m = 0; m < 4; ++m)
#pragma unroll
        for (int n = 0; n < 4; ++n)
          acc[m][n] = __builtin_amdgcn_mfma_f32_16x16x32_f16(af[m], bf[n], acc[m][n], 0, 0, 0);
    }
    __syncthreads();
  }
}

// ---------------- QKV GEMM: q/k/v (f16) = x @ W{q,k,v}^T ----------------
__global__ __launch_bounds__(256) void k_gemm_qkv(const float* __restrict__ x,
    const float* __restrict__ Wq, const float* __restrict__ Wk, const float* __restrict__ Wv,
    f16* __restrict__ q, f16* __restrict__ k, f16* __restrict__ v)
{
  const int z = blockIdx.z;
  const float* Bw = (z == 0) ? Wq : (z == 1) ? Wk : Wv;
  f16* C = (z == 0) ? q : (z == 1) ? k : v;
  f32x4 acc[4][4];
  gemm128<float>(x, Bw, D_, blockIdx.x * 128, blockIdx.y * 128, acc);
  const int tid = threadIdx.x, lane = tid & 63, wid = tid >> 6;
  const int wr = wid >> 1, wc = wid & 1, g = lane >> 4, li = lane & 15;
#pragma unroll
  for (int m = 0; m < 4; ++m)
#pragma unroll
    for (int n = 0; n < 4; ++n)
#pragma unroll
      for (int r = 0; r < 4; ++r) {
        int rr = blockIdx.x * 128 + wr * 64 + m * 16 + g * 4 + r;
        int cc = blockIdx.y * 128 + wc * 64 + n * 16 + li;
        C[(size_t)rr * D_ + cc] = (f16)acc[m][n][r];
      }
}

// ---------------- projection GEMM: out(f32) = oh @ Wp^T + bp ----------------
__global__ __launch_bounds__(256) void k_gemm_proj(const f16* __restrict__ oh,
    const float* __restrict__ Wp, const float* __restrict__ bp, float* __restrict__ out)
{
  f32x4 acc[4][4];
  gemm128<f16>(oh, Wp, D_, blockIdx.x * 128, blockIdx.y * 128, acc);
  const int tid = threadIdx.x, lane = tid & 63, wid = tid >> 6;
  const int wr = wid >> 1, wc = wid & 1, g = lane >> 4, li = lane & 15;
#pragma unroll
  for (int m = 0; m < 4; ++m)
#pragma unroll
    for (int n = 0; n < 4; ++n)
#pragma unroll
      for (int r = 0; r < 4; ++r) {
        int rr = blockIdx.x * 128 + wr * 64 + m * 16 + g * 4 + r;
        int cc = blockIdx.y * 128 + wc * 64 + n * 16 + li;
        out[(size_t)rr * D_ + cc] = acc[m][n][r] + bp[cc];
      }
}

// ---------------- per-head LayerNorm (in place), one wave per 64-chunk ----------------
__global__ __launch_bounds__(256) void k_ln(f16* __restrict__ q, f16* __restrict__ k,
    const float* __restrict__ gq, const float* __restrict__ bq,
    const float* __restrict__ gk, const float* __restrict__ bk)
{
  const int lane = threadIdx.x & 63, wid = threadIdx.x >> 6;
  f16* p = blockIdx.y ? k : q;
  const float* gamma = blockIdx.y ? gk : gq;
  const float* beta  = blockIdx.y ? bk : bq;
  size_t chunk = (size_t)blockIdx.x * 4 + wid;
  f16* base = p + chunk * 64;
  float v = (float)base[lane];
  float s = v;
#pragma unroll
  for (int m = 32; m >= 1; m >>= 1) s += __shfl_xor(s, m);
  float mean = s * (1.f / 64.f);
  float d = v - mean;
  float ss = d * d;
#pragma unroll
  for (int m = 32; m >= 1; m >>= 1) ss += __shfl_xor(ss, m);
  float y = d * rsqrtf(ss * (1.f / 64.f) + 1e-5f) * gamma[lane] + beta[lane];
  base[lane] = (f16)y;
}

// ---------------- V transpose: vh (B,S,D) -> vt (B,H,HD,S) ----------------
__global__ __launch_bounds__(256) void k_transpose_v(const f16* __restrict__ v, f16* __restrict__ vt)
{
  __shared__ f16 T[64][72];
  const int tid = threadIdx.x;
  const int s0 = blockIdx.x * 64, h = blockIdx.y, b = blockIdx.z;
#pragma unroll
  for (int i = 0; i < 2; ++i) {
    int slot = tid + i * 256, sl = slot >> 3, ch = (slot & 7) * 8;
    *(f16x8*)&T[sl][ch] = *(const f16x8*)&v[(size_t)(b * S_ + s0 + sl) * D_ + h * HD_ + ch];
  }
  __syncthreads();
#pragma unroll
  for (int i = 0; i < 2; ++i) {
    int slot = tid + i * 256, d = slot >> 3, sc = (slot & 7) * 8;
    f16x8 val;
#pragma unroll
    for (int j = 0; j < 8; ++j) val[j] = T[sc + j][d];
    *(f16x8*)&vt[((size_t)(b * H_ + h) * HD_ + d) * S_ + s0 + sc] = val;
  }
}

// ---------------- attention pass 1: per-row softmax stats (m, l) ----------------
__global__ __launch_bounds__(256) void k_attn_stats(const f16* __restrict__ qh,
    const f16* __restrict__ kh, float* __restrict__ mbuf, float* __restrict__ lbuf)
{
  __shared__ f16 Ks[128][72];
  __shared__ float Ms[2][128], Ls[2][128];
  const int tq = 15 - blockIdx.x;          // heavy tiles first
  const int bh = blockIdx.y, b = bh >> 4, h = bh & 15;
  const int tid = threadIdx.x, lane = tid & 63, wid = tid >> 6;
  const int wr = wid >> 1, wc = wid & 1, g = lane >> 4, li = lane & 15;

  f16x8 qa[4][2];
#pragma unroll
  for (int m = 0; m < 4; ++m)
#pragma unroll
    for (int kk = 0; kk < 2; ++kk)
      qa[m][kk] = *(const f16x8*)&qh[(size_t)(b * S_ + tq * 128 + wr * 64 + m * 16 + li) * D_
                                     + h * HD_ + kk * 32 + g * 8];

  float mrun[4][4], lrun[4][4];
#pragma unroll
  for (int m = 0; m < 4; ++m)
#pragma unroll
    for (int r = 0; r < 4; ++r) { mrun[m][r] = NEG_BIG; lrun[m][r] = 0.f; }

  for (int tk = 0; tk <= tq; ++tk) {
#pragma unroll
    for (int i = 0; i < 4; ++i) {
      int slot = tid + i * 256, row = slot >> 3, ch = (slot & 7) * 8;
      *(f16x8*)&Ks[row][ch] = *(const f16x8*)&kh[(size_t)(b * S_ + tk * 128 + row) * D_ + h * HD_ + ch];
    }
    __syncthreads();
    f32x4 acc[4][4];
#pragma unroll
    for (int m = 0; m < 4; ++m)
#pragma unroll
      for (int n = 0; n < 4; ++n) acc[m][n] = (f32x4){0.f, 0.f, 0.f, 0.f};
    f16x8 kf[4][2];
#pragma unroll
    for (int n = 0; n < 4; ++n)
#pragma unroll
      for (int kk = 0; kk < 2; ++kk)
        kf[n][kk] = *(const f16x8*)&Ks[wc * 64 + n * 16 + li][kk * 32 + g * 8];
#pragma unroll
    for (int kk = 0; kk < 2; ++kk)
#pragma unroll
      for (int m = 0; m < 4; ++m)
#pragma unroll
        for (int n = 0; n < 4; ++n)
          acc[m][n] = __builtin_amdgcn_mfma_f32_16x16x32_f16(qa[m][kk], kf[n][kk], acc[m][n], 0, 0, 0);

    const bool diag = (tk == tq);
#pragma unroll
    for (int m = 0; m < 4; ++m)
#pragma unroll
      for (int r = 0; r < 4; ++r) {
        int row = tq * 128 + wr * 64 + m * 16 + g * 4 + r;
        float tmax = NEG_BIG;
#pragma unroll
        for (int n = 0; n < 4; ++n) {
          float sv = acc[m][n][r] * SCALE;
          if (diag) { int col = tk * 128 + wc * 64 + n * 16 + li; if (col > row) sv = NEG_BIG; }
          acc[m][n][r] = sv;
          tmax = fmaxf(tmax, sv);
        }
        tmax = red16_max(tmax);
        float mnew = fmaxf(mrun[m][r], tmax);
        if (mnew > -1e29f) {
          float corr = __expf(mrun[m][r] - mnew);
          float ps = 0.f;
#pragma unroll
          for (int n = 0; n < 4; ++n) ps += __expf(acc[m][n][r] - mnew);
          ps = red16_sum(ps);
          lrun[m][r] = lrun[m][r] * corr + ps;
          mrun[m][r] = mnew;
        }
      }
    __syncthreads();
  }

  if (li == 0) {
#pragma unroll
    for (int m = 0; m < 4; ++m)
#pragma unroll
      for (int r = 0; r < 4; ++r) {
        Ms[wc][wr * 64 + m * 16 + g * 4 + r] = mrun[m][r];
        Ls[wc][wr * 64 + m * 16 + g * 4 + r] = lrun[m][r];
      }
  }
  __syncthreads();
  if (tid < 128) {
    float m0 = Ms[0][tid], m1 = Ms[1][tid];
    float l0 = Ls[0][tid], l1 = Ls[1][tid];
    float mf = fmaxf(m0, m1);
    float lf = l0 * __expf(m0 - mf) + l1 * __expf(m1 - mf);
    mbuf[(size_t)bh * S_ + tq * 128 + tid] = mf;
    lbuf[(size_t)bh * S_ + tq * 128 + tid] = lf;
  }
}

// ------------- attention pass 2: write attn (f32) + PV accumulate -> oh (f16) -------------
__global__ __launch_bounds__(256) void k_attn_out(const f16* __restrict__ qh,
    const f16* __restrict__ kh, const f16* __restrict__ vt,
    const float* __restrict__ mbuf, const float* __restrict__ lbuf,
    float* __restrict__ attn, f16* __restrict__ oh)
{
  __shared__ f16 Ks[128][72];
  __shared__ f16 Ps[128][136];
  const int tq = 15 - blockIdx.x;
  const int bh = blockIdx.y, b = bh >> 4, h = bh & 15;
  const int tid = threadIdx.x, lane = tid & 63, wid = tid >> 6;
  const int wr = wid >> 1, wc = wid & 1, g = lane >> 4, li = lane & 15;

  f16x8 qa[4][2];
#pragma unroll
  for (int m = 0; m < 4; ++m)
#pragma unroll
    for (int kk = 0; kk < 2; ++kk)
      qa[m][kk] = *(const f16x8*)&qh[(size_t)(b * S_ + tq * 128 + wr * 64 + m * 16 + li) * D_
                                     + h * HD_ + kk * 32 + g * 8];
  float mrow[4][4], il[4][4];
#pragma unroll
  for (int m = 0; m < 4; ++m)
#pragma unroll
    for (int r = 0; r < 4; ++r) {
      int row = tq * 128 + wr * 64 + m * 16 + g * 4 + r;
      mrow[m][r] = mbuf[(size_t)bh * S_ + row];
      il[m][r] = 1.f / lbuf[(size_t)bh * S_ + row];
    }

  f32x4 oacc[2][4];
#pragma unroll
  for (int pm = 0; pm < 2; ++pm)
#pragma unroll
    for (int n = 0; n < 4; ++n) oacc[pm][n] = (f32x4){0.f, 0.f, 0.f, 0.f};

  for (int tk = 0; tk < 16; ++tk) {
    float* arow0 = attn + ((size_t)bh * S_ + tq * 128) * S_ + tk * 128;
    if (tk <= tq) {
#pragma unroll
      for (int i = 0; i < 4; ++i) {
        int slot = tid + i * 256, row = slot >> 3, ch = (slot & 7) * 8;
        *(f16x8*)&Ks[row][ch] = *(const f16x8*)&kh[(size_t)(b * S_ + tk * 128 + row) * D_ + h * HD_ + ch];
      }
      __syncthreads();
      f32x4 acc[4][4];
#pragma unroll
      for (int m = 0; m < 4; ++m)
#pragma unroll
        for (int n = 0; n < 4; ++n) acc[m][n] = (f32x4){0.f, 0.f, 0.f, 0.f};
      f16x8 kf[4][2];
#pragma unroll
      for (int n = 0; n < 4; ++n)
#pragma unroll
        for (int kk = 0; kk < 2; ++kk)
          kf[n][kk] = *(const f16x8*)&Ks[wc * 64 + n * 16 + li][kk * 32 + g * 8];
#pragma unroll
      for (int kk = 0; kk < 2; ++kk)
#pragma unroll
        for (int m = 0; m < 4; ++m)
#pragma unroll
          for (int n = 0; n < 4; ++n)
            acc[m][n] = __builtin_amdgcn_mfma_f32_16x16x32_f16(qa[m][kk], kf[n][kk], acc[m][n], 0, 0, 0);

      const bool diag = (tk == tq);
#pragma unroll
      for (int m = 0; m < 4; ++m)
#pragma unroll
        for (int r = 0; r < 4; ++r) {
          int row = tq * 128 + wr * 64 + m * 16 + g * 4 + r;
#pragma unroll
          for (int n = 0; n < 4; ++n) {
            float sv = acc[m][n][r] * SCALE;
            if (diag) { int col = tk * 128 + wc * 64 + n * 16 + li; if (col > row) sv = NEG_BIG; }
            float p = __expf(sv - mrow[m][r]) * il[m][r];
            Ps[wr * 64 + m * 16 + g * 4 + r][wc * 64 + n * 16 + li] = (f16)p;
          }
        }
      __syncthreads();
      // coalesced attn write from LDS (f16 -> f32)
      {
        int row = tid >> 1, colh = (tid & 1) * 64;
        float* dst = arow0 + (size_t)row * S_ + colh;
#pragma unroll
        for (int j = 0; j < 8; ++j) {
          f16x8 hv = *(const f16x8*)&Ps[row][colh + j * 8];
          f32x4 lo = {(float)hv[0], (float)hv[1], (float)hv[2], (float)hv[3]};
          f32x4 hi = {(float)hv[4], (float)hv[5], (float)hv[6], (float)hv[7]};
          *(f32x4*)(dst + j * 8) = lo;
          *(f32x4*)(dst + j * 8 + 4) = hi;
        }
      }
      // PV: oacc += P @ V  (waves split the 128 rows 4-ways)
#pragma unroll
      for (int kk = 0; kk < 4; ++kk) {
        f16x8 vbf[4];
#pragma unroll
        for (int n = 0; n < 4; ++n)
          vbf[n] = *(const f16x8*)&vt[((size_t)bh * HD_ + n * 16 + li) * S_ + tk * 128 + kk * 32 + g * 8];
#pragma unroll
        for (int pm = 0; pm < 2; ++pm) {
          f16x8 pa = *(const f16x8*)&Ps[wid * 32 + pm * 16 + li][kk * 32 + g * 8];
#pragma unroll
          for (int n = 0; n < 4; ++n)
            oacc[pm][n] = __builtin_amdgcn_mfma_f32_16x16x32_f16(pa, vbf[n], oacc[pm][n], 0, 0, 0);
        }
      }
      __syncthreads();
    } else {
      // strictly-above-diagonal tile: attn = 0 (harness poisons d_out; must write)
      int row = tid >> 1, colh = (tid & 1) * 64;
      float* dst = arow0 + (size_t)row * S_ + colh;
      f32x4 z = {0.f, 0.f, 0.f, 0.f};
#pragma unroll
      for (int j = 0; j < 16; ++j) *(f32x4*)(dst + j * 4) = z;
    }
  }
  // write per-head output rows (B,S,D layout so proj GEMM consumes directly)
#pragma unroll
  for (int pm = 0; pm < 2; ++pm)
#pragma unroll
    for (int n = 0; n < 4; ++n)
#pragma unroll
      for (int r = 0; r < 4; ++r) {
        int row = tq * 128 + wid * 32 + pm * 16 + g * 4 + r;
        oh[(size_t)(b * S_ + row) * D_ + h * HD_ + n * 16 + li] = (f16)oacc[pm][n][r];
      }
}

extern "C" void kernel_launch(void* const* d_in, const int* in_sizes, int n_in,
                              void* d_out, int out_size, void* d_ws, size_t ws_size,
                              hipStream_t stream)
{
  (void)in_sizes; (void)n_in; (void)out_size; (void)ws_size;
  const float* x  = (const float*)d_in[0];
  const float* Wq = (const float*)d_in[1];
  const float* Wk = (const float*)d_in[2];
  const float* Wv = (const float*)d_in[3];
  const float* Wp = (const float*)d_in[4];
  const float* bp = (const float*)d_in[5];
  const float* gq = (const float*)d_in[6];
  const float* bq = (const float*)d_in[7];
  const float* gk = (const float*)d_in[8];
  const float* bk = (const float*)d_in[9];

  float* out  = (float*)d_out;
  float* attn = out + (size_t)B_ * S_ * D_;

  f16* qh = (f16*)d_ws;
  f16* kh = qh + (size_t)M_ * D_;
  f16* vh = kh + (size_t)M_ * D_;
  f16* vt = vh + (size_t)M_ * D_;
  f16* oh = vt + (size_t)M_ * D_;
  float* mbuf = (float*)(oh + (size_t)M_ * D_);
  float* lbuf = mbuf + (size_t)B_ * H_ * S_;

  dim3 blk(256);
  k_gemm_qkv<<<dim3(32, 8, 3), blk, 0, stream>>>(x, Wq, Wk, Wv, qh, kh, vh);
  k_ln<<<dim3(16384, 2), blk, 0, stream>>>(qh, kh, gq, bq, gk, bk);
  k_transpose_v<<<dim3(32, 16, 2), blk, 0, stream>>>(vh, vt);
  k_attn_stats<<<dim3(16, 32), blk, 0, stream>>>(qh, kh, mbuf, lbuf);
  k_attn_out<<<dim3(16, 32), blk, 0, stream>>>(qh, kh, vt, mbuf, lbuf, attn, oh);
  k_gemm_proj<<<dim3(32, 8), blk, 0, stream>>>(oh, Wp, bp, out);
}

// Round 2
// 458.682 us; speedup vs baseline: 1.3208x; 1.3208x over previous
//
#include <hip/hip_runtime.h>

typedef _Float16 f16;
typedef _Float16 f16x4 __attribute__((ext_vector_type(4)));
typedef _Float16 f16x8 __attribute__((ext_vector_type(8)));
typedef float f32x4 __attribute__((ext_vector_type(4)));

#define D_ 1024
#define H_ 16
#define HD_ 64
#define B_ 2
#define S_ 2048
#define M_ 4096          // B_*S_
#define SCALE 0.125f
#define NEG_BIG -1e30f

__device__ __forceinline__ float red16_sum(float v) {
#pragma unroll
  for (int m = 8; m >= 1; m >>= 1) v += __shfl_xor(v, m);
  return v;
}

// ---------------- 128x128 GEMM tile body: C = A(MxK) * Bw(NxK)^T ----------------
template<typename TA>
__device__ __forceinline__ void gemm128(const TA* __restrict__ A, const float* __restrict__ Bw,
                                        int K, int bm, int bn, f32x4 acc[4][4])
{
  __shared__ f16 As[128][72];
  __shared__ f16 Bs[128][72];
  const int tid = threadIdx.x;
  const int lane = tid & 63, wid = tid >> 6;
  const int wr = wid >> 1, wc = wid & 1, g = lane >> 4, li = lane & 15;

#pragma unroll
  for (int m = 0; m < 4; ++m)
#pragma unroll
    for (int n = 0; n < 4; ++n)
      acc[m][n] = (f32x4){0.f, 0.f, 0.f, 0.f};

  for (int k0 = 0; k0 < K; k0 += 64) {
#pragma unroll
    for (int i = 0; i < 4; ++i) {
      int slot = tid + i * 256;
      int row = slot >> 3, ch = (slot & 7) * 8;
      f16x8 av;
      if constexpr (sizeof(TA) == 4) {
        const f32x4* p = (const f32x4*)((const float*)A + (size_t)(bm + row) * K + k0 + ch);
        f32x4 u0 = p[0], u1 = p[1];
#pragma unroll
        for (int j = 0; j < 4; ++j) { av[j] = (f16)u0[j]; av[j + 4] = (f16)u1[j]; }
      } else {
        av = *(const f16x8*)((const f16*)A + (size_t)(bm + row) * K + k0 + ch);
      }
      *(f16x8*)&As[row][ch] = av;
      const f32x4* pb = (const f32x4*)(Bw + (size_t)(bn + row) * K + k0 + ch);
      f32x4 v0 = pb[0], v1 = pb[1];
      f16x8 bv;
#pragma unroll
      for (int j = 0; j < 4; ++j) { bv[j] = (f16)v0[j]; bv[j + 4] = (f16)v1[j]; }
      *(f16x8*)&Bs[row][ch] = bv;
    }
    __syncthreads();
#pragma unroll
    for (int kk = 0; kk < 64; kk += 32) {
      f16x8 af[4], bf[4];
#pragma unroll
      for (int m = 0; m < 4; ++m) af[m] = *(const f16x8*)&As[wr * 64 + m * 16 + li][kk + g * 8];
#pragma unroll
      for (int n = 0; n < 4; ++n) bf[n] = *(const f16x8*)&Bs[wc * 64 + n * 16 + li][kk + g * 8];
#pragma unroll
      for (int m = 0; m < 4; ++m)
#pragma unroll
        for (int n = 0; n < 4; ++n)
          acc[m][n] = __builtin_amdgcn_mfma_f32_16x16x32_f16(af[m], bf[n], acc[m][n], 0, 0, 0);
    }
    __syncthreads();
  }
}

// ---------------- QKV GEMM: q/k/v (f16) = x @ W{q,k,v}^T ----------------
__global__ __launch_bounds__(256) void k_gemm_qkv(const float* __restrict__ x,
    const float* __restrict__ Wq, const float* __restrict__ Wk, const float* __restrict__ Wv,
    f16* __restrict__ q, f16* __restrict__ k, f16* __restrict__ v)
{
  const int z = blockIdx.z;
  const float* Bw = (z == 0) ? Wq : (z == 1) ? Wk : Wv;
  f16* C = (z == 0) ? q : (z == 1) ? k : v;
  f32x4 acc[4][4];
  gemm128<float>(x, Bw, D_, blockIdx.x * 128, blockIdx.y * 128, acc);
  const int tid = threadIdx.x, lane = tid & 63, wid = tid >> 6;
  const int wr = wid >> 1, wc = wid & 1, g = lane >> 4, li = lane & 15;
#pragma unroll
  for (int m = 0; m < 4; ++m)
#pragma unroll
    for (int n = 0; n < 4; ++n)
#pragma unroll
      for (int r = 0; r < 4; ++r) {
        int rr = blockIdx.x * 128 + wr * 64 + m * 16 + g * 4 + r;
        int cc = blockIdx.y * 128 + wc * 64 + n * 16 + li;
        C[(size_t)rr * D_ + cc] = (f16)acc[m][n][r];
      }
}

// ---------------- projection GEMM: out(f32) = oh @ Wp^T + bp ----------------
__global__ __launch_bounds__(256) void k_gemm_proj(const f16* __restrict__ oh,
    const float* __restrict__ Wp, const float* __restrict__ bp, float* __restrict__ out)
{
  f32x4 acc[4][4];
  gemm128<f16>(oh, Wp, D_, blockIdx.x * 128, blockIdx.y * 128, acc);
  const int tid = threadIdx.x, lane = tid & 63, wid = tid >> 6;
  const int wr = wid >> 1, wc = wid & 1, g = lane >> 4, li = lane & 15;
#pragma unroll
  for (int m = 0; m < 4; ++m)
#pragma unroll
    for (int n = 0; n < 4; ++n)
#pragma unroll
      for (int r = 0; r < 4; ++r) {
        int rr = blockIdx.x * 128 + wr * 64 + m * 16 + g * 4 + r;
        int cc = blockIdx.y * 128 + wc * 64 + n * 16 + li;
        out[(size_t)rr * D_ + cc] = acc[m][n][r] + bp[cc];
      }
}

// ---------------- per-head LayerNorm (in place), one wave per 64-chunk ----------------
__global__ __launch_bounds__(256) void k_ln(f16* __restrict__ q, f16* __restrict__ k,
    const float* __restrict__ gq, const float* __restrict__ bq,
    const float* __restrict__ gk, const float* __restrict__ bk)
{
  const int lane = threadIdx.x & 63, wid = threadIdx.x >> 6;
  f16* p = blockIdx.y ? k : q;
  const float* gamma = blockIdx.y ? gk : gq;
  const float* beta  = blockIdx.y ? bk : bq;
  size_t chunk = (size_t)blockIdx.x * 4 + wid;
  f16* base = p + chunk * 64;
  float v = (float)base[lane];
  float s = v;
#pragma unroll
  for (int m = 32; m >= 1; m >>= 1) s += __shfl_xor(s, m);
  float mean = s * (1.f / 64.f);
  float d = v - mean;
  float ss = d * d;
#pragma unroll
  for (int m = 32; m >= 1; m >>= 1) ss += __shfl_xor(ss, m);
  float y = d * rsqrtf(ss * (1.f / 64.f) + 1e-5f) * gamma[lane] + beta[lane];
  base[lane] = (f16)y;
}

// ---------------- V transpose: vh (B,S,D) -> vt (B,H,HD,S) ----------------
__global__ __launch_bounds__(256) void k_transpose_v(const f16* __restrict__ v, f16* __restrict__ vt)
{
  __shared__ f16 T[64][72];
  const int tid = threadIdx.x;
  const int s0 = blockIdx.x * 64, h = blockIdx.y, b = blockIdx.z;
#pragma unroll
  for (int i = 0; i < 2; ++i) {
    int slot = tid + i * 256, sl = slot >> 3, ch = (slot & 7) * 8;
    *(f16x8*)&T[sl][ch] = *(const f16x8*)&v[(size_t)(b * S_ + s0 + sl) * D_ + h * HD_ + ch];
  }
  __syncthreads();
#pragma unroll
  for (int i = 0; i < 2; ++i) {
    int slot = tid + i * 256, d = slot >> 3, sc = (slot & 7) * 8;
    f16x8 val;
#pragma unroll
    for (int j = 0; j < 8; ++j) val[j] = T[sc + j][d];
    *(f16x8*)&vt[((size_t)(b * H_ + h) * HD_ + d) * S_ + s0 + sc] = val;
  }
}

// ---------------- zero-fill of strictly-upper attn region ----------------
__global__ __launch_bounds__(256) void k_attn_zero(float* __restrict__ attn)
{
  const int tq = blockIdx.x, bh = blockIdx.y;
  const int ntk = (tq + 2) >> 1;          // # of 128-col k-tiles attn_out covers
  const int zstart = ntk * 128;
  const int tid = threadIdx.x;
  const int r0 = tid >> 5, c0 = (tid & 31) * 4;
  float* base = attn + ((size_t)bh * S_ + tq * 64) * S_;
  f32x4 z = {0.f, 0.f, 0.f, 0.f};
  for (int c = zstart; c < S_; c += 128)
#pragma unroll
    for (int r = 0; r < 64; r += 8)
      *(f32x4*)(base + (size_t)(r + r0) * S_ + c + c0) = z;
}

// ---------------- attention pass 1: per-row denominators l = sum exp(s) ----------------
// 64-row q-tiles, 128-col k-tiles. No max subtraction: LN'd q,k => |s| <= 8.
__global__ __launch_bounds__(256, 4) void k_attn_stats(const f16* __restrict__ qh,
    const f16* __restrict__ kh, float* __restrict__ lbuf)
{
  __shared__ f16 Ks[128][72];
  __shared__ float Ls[2][64];
  const int tq = 31 - blockIdx.x;          // heavy tiles first
  const int bh = blockIdx.y, b = bh >> 4, h = bh & 15;
  const int tid = threadIdx.x, lane = tid & 63, wid = tid >> 6;
  const int wr = wid >> 1, wc = wid & 1, g = lane >> 4, li = lane & 15;
  const int ntk = (tq + 2) >> 1;

  f16x8 qa[2][2];
#pragma unroll
  for (int m = 0; m < 2; ++m)
#pragma unroll
    for (int kk = 0; kk < 2; ++kk)
      qa[m][kk] = *(const f16x8*)&qh[(size_t)(b * S_ + tq * 64 + wr * 32 + m * 16 + li) * D_
                                     + h * HD_ + kk * 32 + g * 8];
  float lrun[2][4];
#pragma unroll
  for (int m = 0; m < 2; ++m)
#pragma unroll
    for (int r = 0; r < 4; ++r) lrun[m][r] = 0.f;

  for (int tk = 0; tk < ntk; ++tk) {
#pragma unroll
    for (int i = 0; i < 4; ++i) {
      int slot = tid + i * 256, row = slot >> 3, ch = (slot & 7) * 8;
      *(f16x8*)&Ks[row][ch] = *(const f16x8*)&kh[(size_t)(b * S_ + tk * 128 + row) * D_ + h * HD_ + ch];
    }
    __syncthreads();
    f32x4 acc[2][4];
#pragma unroll
    for (int m = 0; m < 2; ++m)
#pragma unroll
      for (int n = 0; n < 4; ++n) acc[m][n] = (f32x4){0.f, 0.f, 0.f, 0.f};
    f16x8 kf[4][2];
#pragma unroll
    for (int n = 0; n < 4; ++n)
#pragma unroll
      for (int kk = 0; kk < 2; ++kk)
        kf[n][kk] = *(const f16x8*)&Ks[wc * 64 + n * 16 + li][kk * 32 + g * 8];
#pragma unroll
    for (int kk = 0; kk < 2; ++kk)
#pragma unroll
      for (int m = 0; m < 2; ++m)
#pragma unroll
        for (int n = 0; n < 4; ++n)
          acc[m][n] = __builtin_amdgcn_mfma_f32_16x16x32_f16(qa[m][kk], kf[n][kk], acc[m][n], 0, 0, 0);

    const bool diag = (tk == ntk - 1);
#pragma unroll
    for (int m = 0; m < 2; ++m)
#pragma unroll
      for (int r = 0; r < 4; ++r) {
        int row = tq * 64 + wr * 32 + m * 16 + g * 4 + r;
        float ps = 0.f;
#pragma unroll
        for (int n = 0; n < 4; ++n) {
          float sv = acc[m][n][r] * SCALE;
          if (diag) { int col = tk * 128 + wc * 64 + n * 16 + li; if (col > row) sv = NEG_BIG; }
          ps += __expf(sv);
        }
        lrun[m][r] += red16_sum(ps);
      }
    __syncthreads();
  }

  if (li == 0) {
#pragma unroll
    for (int m = 0; m < 2; ++m)
#pragma unroll
      for (int r = 0; r < 4; ++r)
        Ls[wc][wr * 32 + m * 16 + g * 4 + r] = lrun[m][r];
  }
  __syncthreads();
  if (tid < 64) lbuf[(size_t)bh * S_ + tq * 64 + tid] = Ls[0][tid] + Ls[1][tid];
}

// ------------- attention pass 2: write attn (f32) + PV accumulate -> oh (f16) -------------
__global__ __launch_bounds__(256, 4) void k_attn_out(const f16* __restrict__ qh,
    const f16* __restrict__ kh, const f16* __restrict__ vt,
    const float* __restrict__ lbuf, float* __restrict__ attn, f16* __restrict__ oh)
{
  __shared__ f16 Ks[128][72];
  __shared__ f16 Ps[64][136];
  const int tq = 31 - blockIdx.x;
  const int bh = blockIdx.y, b = bh >> 4, h = bh & 15;
  const int tid = threadIdx.x, lane = tid & 63, wid = tid >> 6;
  const int wr = wid >> 1, wc = wid & 1, g = lane >> 4, li = lane & 15;
  const int ntk = (tq + 2) >> 1;

  f16x8 qa[2][2];
#pragma unroll
  for (int m = 0; m < 2; ++m)
#pragma unroll
    for (int kk = 0; kk < 2; ++kk)
      qa[m][kk] = *(const f16x8*)&qh[(size_t)(b * S_ + tq * 64 + wr * 32 + m * 16 + li) * D_
                                     + h * HD_ + kk * 32 + g * 8];
  float il[2][4];
#pragma unroll
  for (int m = 0; m < 2; ++m)
#pragma unroll
    for (int r = 0; r < 4; ++r) {
      int row = tq * 64 + wr * 32 + m * 16 + g * 4 + r;
      il[m][r] = 1.f / lbuf[(size_t)bh * S_ + row];
    }

  f32x4 oacc[4];
#pragma unroll
  for (int n = 0; n < 4; ++n) oacc[n] = (f32x4){0.f, 0.f, 0.f, 0.f};

  const int r0 = tid >> 5, c0 = (tid & 31) * 4;

  for (int tk = 0; tk < ntk; ++tk) {
#pragma unroll
    for (int i = 0; i < 4; ++i) {
      int slot = tid + i * 256, row = slot >> 3, ch = (slot & 7) * 8;
      *(f16x8*)&Ks[row][ch] = *(const f16x8*)&kh[(size_t)(b * S_ + tk * 128 + row) * D_ + h * HD_ + ch];
    }
    __syncthreads();
    f32x4 acc[2][4];
#pragma unroll
    for (int m = 0; m < 2; ++m)
#pragma unroll
      for (int n = 0; n < 4; ++n) acc[m][n] = (f32x4){0.f, 0.f, 0.f, 0.f};
    f16x8 kf[4][2];
#pragma unroll
    for (int n = 0; n < 4; ++n)
#pragma unroll
      for (int kk = 0; kk < 2; ++kk)
        kf[n][kk] = *(const f16x8*)&Ks[wc * 64 + n * 16 + li][kk * 32 + g * 8];
#pragma unroll
    for (int kk = 0; kk < 2; ++kk)
#pragma unroll
      for (int m = 0; m < 2; ++m)
#pragma unroll
        for (int n = 0; n < 4; ++n)
          acc[m][n] = __builtin_amdgcn_mfma_f32_16x16x32_f16(qa[m][kk], kf[n][kk], acc[m][n], 0, 0, 0);

    const bool diag = (tk == ntk - 1);
#pragma unroll
    for (int m = 0; m < 2; ++m)
#pragma unroll
      for (int r = 0; r < 4; ++r) {
        int row = tq * 64 + wr * 32 + m * 16 + g * 4 + r;
#pragma unroll
        for (int n = 0; n < 4; ++n) {
          float sv = acc[m][n][r] * SCALE;
          if (diag) { int col = tk * 128 + wc * 64 + n * 16 + li; if (col > row) sv = NEG_BIG; }
          float p = __expf(sv) * il[m][r];
          Ps[wr * 32 + m * 16 + g * 4 + r][wc * 64 + n * 16 + li] = (f16)p;
        }
      }
    __syncthreads();

    // coalesced attn write from LDS: 64 rows x 128 cols, 32 lanes span one row
    {
      float* arow0 = attn + ((size_t)bh * S_ + tq * 64) * S_ + tk * 128;
#pragma unroll
      for (int rr = 0; rr < 64; rr += 8) {
        int row = rr + r0;
        f16x4 hv = *(const f16x4*)&Ps[row][c0];
        f32x4 fv = {(float)hv[0], (float)hv[1], (float)hv[2], (float)hv[3]};
        *(f32x4*)(arow0 + (size_t)row * S_ + c0) = fv;
      }
    }

    // PV: wave wid owns rows wid*16..+15 of the 64-row out tile
#pragma unroll
    for (int kk = 0; kk < 4; ++kk) {
      f16x8 vbf[4];
#pragma unroll
      for (int n = 0; n < 4; ++n)
        vbf[n] = *(const f16x8*)&vt[((size_t)bh * HD_ + n * 16 + li) * S_ + tk * 128 + kk * 32 + g * 8];
      f16x8 pa = *(const f16x8*)&Ps[wid * 16 + li][kk * 32 + g * 8];
#pragma unroll
      for (int n = 0; n < 4; ++n)
        oacc[n] = __builtin_amdgcn_mfma_f32_16x16x32_f16(pa, vbf[n], oacc[n], 0, 0, 0);
    }
    __syncthreads();
  }

  // write per-head output rows (B,S,D layout so proj GEMM consumes directly)
#pragma unroll
  for (int n = 0; n < 4; ++n)
#pragma unroll
    for (int r = 0; r < 4; ++r) {
      int row = tq * 64 + wid * 16 + g * 4 + r;
      oh[(size_t)(b * S_ + row) * D_ + h * HD_ + n * 16 + li] = (f16)oacc[n][r];
    }
}

extern "C" void kernel_launch(void* const* d_in, const int* in_sizes, int n_in,
                              void* d_out, int out_size, void* d_ws, size_t ws_size,
                              hipStream_t stream)
{
  (void)in_sizes; (void)n_in; (void)out_size; (void)ws_size;
  const float* x  = (const float*)d_in[0];
  const float* Wq = (const float*)d_in[1];
  const float* Wk = (const float*)d_in[2];
  const float* Wv = (const float*)d_in[3];
  const float* Wp = (const float*)d_in[4];
  const float* bp = (const float*)d_in[5];
  const float* gq = (const float*)d_in[6];
  const float* bq = (const float*)d_in[7];
  const float* gk = (const float*)d_in[8];
  const float* bk = (const float*)d_in[9];

  float* out  = (float*)d_out;
  float* attn = out + (size_t)B_ * S_ * D_;

  f16* qh = (f16*)d_ws;
  f16* kh = qh + (size_t)M_ * D_;
  f16* vh = kh + (size_t)M_ * D_;
  f16* vt = vh + (size_t)M_ * D_;
  f16* oh = vt + (size_t)M_ * D_;
  float* lbuf = (float*)(oh + (size_t)M_ * D_);

  dim3 blk(256);
  k_gemm_qkv<<<dim3(32, 8, 3), blk, 0, stream>>>(x, Wq, Wk, Wv, qh, kh, vh);
  k_ln<<<dim3(16384, 2), blk, 0, stream>>>(qh, kh, gq, bq, gk, bk);
  k_transpose_v<<<dim3(32, 16, 2), blk, 0, stream>>>(vh, vt);
  k_attn_zero<<<dim3(32, 32), blk, 0, stream>>>(attn);
  k_attn_stats<<<dim3(32, 32), blk, 0, stream>>>(qh, kh, lbuf);
  k_attn_out<<<dim3(32, 32), blk, 0, stream>>>(qh, kh, vt, lbuf, attn, oh);
  k_gemm_proj<<<dim3(32, 8), blk, 0, stream>>>(oh, Wp, bp, out);
}

// Round 3
// 420.868 us; speedup vs baseline: 1.4394x; 1.0898x over previous
//
#include <hip/hip_runtime.h>

typedef _Float16 f16;
typedef _Float16 f16x4 __attribute__((ext_vector_type(4)));
typedef _Float16 f16x8 __attribute__((ext_vector_type(8)));
typedef float f32x4 __attribute__((ext_vector_type(4)));

#define D_ 1024
#define H_ 16
#define HD_ 64
#define B_ 2
#define S_ 2048
#define M_ 4096          // B_*S_
#define SCALE 0.125f
#define NEG_BIG -1e30f

__device__ __forceinline__ float red16_sum(float v) {
#pragma unroll
  for (int m = 8; m >= 1; m >>= 1) v += __shfl_xor(v, m);
  return v;
}

// ---------------- 128x128 GEMM tile body: C = A(MxK) * Bw(NxK)^T ----------------
template<typename TA>
__device__ __forceinline__ void gemm128(const TA* __restrict__ A, const float* __restrict__ Bw,
                                        int K, int bm, int bn, f32x4 acc[4][4])
{
  __shared__ f16 As[128][72];
  __shared__ f16 Bs[128][72];
  const int tid = threadIdx.x;
  const int lane = tid & 63, wid = tid >> 6;
  const int wr = wid >> 1, wc = wid & 1, g = lane >> 4, li = lane & 15;

#pragma unroll
  for (int m = 0; m < 4; ++m)
#pragma unroll
    for (int n = 0; n < 4; ++n)
      acc[m][n] = (f32x4){0.f, 0.f, 0.f, 0.f};

  for (int k0 = 0; k0 < K; k0 += 64) {
#pragma unroll
    for (int i = 0; i < 4; ++i) {
      int slot = tid + i * 256;
      int row = slot >> 3, ch = (slot & 7) * 8;
      f16x8 av;
      if constexpr (sizeof(TA) == 4) {
        const f32x4* p = (const f32x4*)((const float*)A + (size_t)(bm + row) * K + k0 + ch);
        f32x4 u0 = p[0], u1 = p[1];
#pragma unroll
        for (int j = 0; j < 4; ++j) { av[j] = (f16)u0[j]; av[j + 4] = (f16)u1[j]; }
      } else {
        av = *(const f16x8*)((const f16*)A + (size_t)(bm + row) * K + k0 + ch);
      }
      *(f16x8*)&As[row][ch] = av;
      const f32x4* pb = (const f32x4*)(Bw + (size_t)(bn + row) * K + k0 + ch);
      f32x4 v0 = pb[0], v1 = pb[1];
      f16x8 bv;
#pragma unroll
      for (int j = 0; j < 4; ++j) { bv[j] = (f16)v0[j]; bv[j + 4] = (f16)v1[j]; }
      *(f16x8*)&Bs[row][ch] = bv;
    }
    __syncthreads();
#pragma unroll
    for (int kk = 0; kk < 64; kk += 32) {
      f16x8 af[4], bf[4];
#pragma unroll
      for (int m = 0; m < 4; ++m) af[m] = *(const f16x8*)&As[wr * 64 + m * 16 + li][kk + g * 8];
#pragma unroll
      for (int n = 0; n < 4; ++n) bf[n] = *(const f16x8*)&Bs[wc * 64 + n * 16 + li][kk + g * 8];
#pragma unroll
      for (int m = 0; m < 4; ++m)
#pragma unroll
        for (int n = 0; n < 4; ++n)
          acc[m][n] = __builtin_amdgcn_mfma_f32_16x16x32_f16(af[m], bf[n], acc[m][n], 0, 0, 0);
    }
    __syncthreads();
  }
}

// ------- QKV GEMM with fused per-head LayerNorm (q,k); head-major outputs [B,H,S,HD] -------
__global__ __launch_bounds__(256) void k_gemm_qkv(const float* __restrict__ x,
    const float* __restrict__ Wq, const float* __restrict__ Wk, const float* __restrict__ Wv,
    const float* __restrict__ gq, const float* __restrict__ bq,
    const float* __restrict__ gk, const float* __restrict__ bk,
    f16* __restrict__ qt, f16* __restrict__ kt, f16* __restrict__ vh)
{
  const int z = blockIdx.z;
  const float* Bw = (z == 0) ? Wq : (z == 1) ? Wk : Wv;
  f16* C = (z == 0) ? qt : (z == 1) ? kt : vh;
  f32x4 acc[4][4];
  gemm128<float>(x, Bw, D_, blockIdx.x * 128, blockIdx.y * 128, acc);
  const int tid = threadIdx.x, lane = tid & 63, wid = tid >> 6;
  const int wr = wid >> 1, wc = wid & 1, g = lane >> 4, li = lane & 15;
  const int hh = blockIdx.y * 2 + wc;      // head index this wave writes
  const float* gamma = (z == 0) ? gq : gk;
  const float* beta  = (z == 0) ? bq : bk;
  float gm[4], bt[4];
  if (z < 2) {
#pragma unroll
    for (int n = 0; n < 4; ++n) { gm[n] = gamma[n * 16 + li]; bt[n] = beta[n * 16 + li]; }
  }
#pragma unroll
  for (int m = 0; m < 4; ++m)
#pragma unroll
    for (int r = 0; r < 4; ++r) {
      int rr = blockIdx.x * 128 + wr * 64 + m * 16 + g * 4 + r;
      int b = rr >> 11, s = rr & (S_ - 1);
      float v0 = acc[m][0][r], v1 = acc[m][1][r], v2 = acc[m][2][r], v3 = acc[m][3][r];
      if (z < 2) {
        // LayerNorm over the 64 head cols: 16-lane reduce, 4 vals/lane
        float mean = red16_sum(v0 + v1 + v2 + v3) * (1.f / 64.f);
        v0 -= mean; v1 -= mean; v2 -= mean; v3 -= mean;
        float ss = red16_sum(v0 * v0 + v1 * v1 + v2 * v2 + v3 * v3);
        float inv = rsqrtf(ss * (1.f / 64.f) + 1e-5f);
        v0 = v0 * inv * gm[0] + bt[0]; v1 = v1 * inv * gm[1] + bt[1];
        v2 = v2 * inv * gm[2] + bt[2]; v3 = v3 * inv * gm[3] + bt[3];
      }
      f16* dst = C + ((size_t)(b * H_ + hh) * S_ + s) * HD_;
      dst[li]      = (f16)v0;
      dst[16 + li] = (f16)v1;
      dst[32 + li] = (f16)v2;
      dst[48 + li] = (f16)v3;
    }
}

// ---------------- projection GEMM: out(f32) = oh @ Wp^T + bp ----------------
__global__ __launch_bounds__(256) void k_gemm_proj(const f16* __restrict__ oh,
    const float* __restrict__ Wp, const float* __restrict__ bp, float* __restrict__ out)
{
  f32x4 acc[4][4];
  gemm128<f16>(oh, Wp, D_, blockIdx.x * 128, blockIdx.y * 128, acc);
  const int tid = threadIdx.x, lane = tid & 63, wid = tid >> 6;
  const int wr = wid >> 1, wc = wid & 1, g = lane >> 4, li = lane & 15;
#pragma unroll
  for (int m = 0; m < 4; ++m)
#pragma unroll
    for (int n = 0; n < 4; ++n)
#pragma unroll
      for (int r = 0; r < 4; ++r) {
        int rr = blockIdx.x * 128 + wr * 64 + m * 16 + g * 4 + r;
        int cc = blockIdx.y * 128 + wc * 64 + n * 16 + li;
        out[(size_t)rr * D_ + cc] = acc[m][n][r] + bp[cc];
      }
}

// ---------------- V transpose: vh (B,H,S,HD) -> vt (B,H,HD,S) ----------------
__global__ __launch_bounds__(256) void k_transpose_v(const f16* __restrict__ vh, f16* __restrict__ vt)
{
  __shared__ f16 T[64][72];
  const int tid = threadIdx.x;
  const int s0 = blockIdx.x * 64, h = blockIdx.y, b = blockIdx.z;
  const f16* src = vh + ((size_t)(b * H_ + h) * S_ + s0) * HD_;
#pragma unroll
  for (int i = 0; i < 2; ++i) {
    int slot = tid + i * 256, sl = slot >> 3, ch = (slot & 7) * 8;
    *(f16x8*)&T[sl][ch] = *(const f16x8*)&src[(size_t)sl * HD_ + ch];
  }
  __syncthreads();
#pragma unroll
  for (int i = 0; i < 2; ++i) {
    int slot = tid + i * 256, d = slot >> 3, sc = (slot & 7) * 8;
    f16x8 val;
#pragma unroll
    for (int j = 0; j < 8; ++j) val[j] = T[sc + j][d];
    *(f16x8*)&vt[((size_t)(b * H_ + h) * HD_ + d) * S_ + s0 + sc] = val;
  }
}

// ------------- attention pass 1: row denominators l = sum exp(s); K direct from L2 -------------
__global__ __launch_bounds__(256, 4) void k_attn_stats(const f16* __restrict__ qt,
    const f16* __restrict__ kt, float* __restrict__ lbuf)
{
  __shared__ float Ls[2][64];
  const int tq = 31 - blockIdx.x;          // heavy tiles first
  const int bh = blockIdx.y;
  const int tid = threadIdx.x, lane = tid & 63, wid = tid >> 6;
  const int wr = wid >> 1, wc = wid & 1, g = lane >> 4, li = lane & 15;
  const int ntk = (tq + 2) >> 1;
  const f16* Qb = qt + (size_t)bh * S_ * HD_;
  const f16* Kb = kt + (size_t)bh * S_ * HD_;

  f16x8 qa[2][2];
#pragma unroll
  for (int m = 0; m < 2; ++m)
#pragma unroll
    for (int kk = 0; kk < 2; ++kk)
      qa[m][kk] = *(const f16x8*)&Qb[(size_t)(tq * 64 + wr * 32 + m * 16 + li) * HD_ + kk * 32 + g * 8];

  float lrun[2][4];
#pragma unroll
  for (int m = 0; m < 2; ++m)
#pragma unroll
    for (int r = 0; r < 4; ++r) lrun[m][r] = 0.f;

  for (int tk = 0; tk < ntk; ++tk) {
    f16x8 kf[4][2];
#pragma unroll
    for (int n = 0; n < 4; ++n)
#pragma unroll
      for (int kk = 0; kk < 2; ++kk)
        kf[n][kk] = *(const f16x8*)&Kb[(size_t)(tk * 128 + wc * 64 + n * 16 + li) * HD_ + kk * 32 + g * 8];
    f32x4 acc[2][4];
#pragma unroll
    for (int m = 0; m < 2; ++m)
#pragma unroll
      for (int n = 0; n < 4; ++n) acc[m][n] = (f32x4){0.f, 0.f, 0.f, 0.f};
#pragma unroll
    for (int kk = 0; kk < 2; ++kk)
#pragma unroll
      for (int m = 0; m < 2; ++m)
#pragma unroll
        for (int n = 0; n < 4; ++n)
          acc[m][n] = __builtin_amdgcn_mfma_f32_16x16x32_f16(qa[m][kk], kf[n][kk], acc[m][n], 0, 0, 0);

    const bool diag = (tk == ntk - 1);
#pragma unroll
    for (int m = 0; m < 2; ++m)
#pragma unroll
      for (int r = 0; r < 4; ++r) {
        int row = tq * 64 + wr * 32 + m * 16 + g * 4 + r;
        float ps = 0.f;
#pragma unroll
        for (int n = 0; n < 4; ++n) {
          float sv = acc[m][n][r] * SCALE;
          if (diag) { int col = tk * 128 + wc * 64 + n * 16 + li; if (col > row) sv = NEG_BIG; }
          ps += __expf(sv);
        }
        lrun[m][r] += red16_sum(ps);
      }
  }

  if (li == 0) {
#pragma unroll
    for (int m = 0; m < 2; ++m)
#pragma unroll
      for (int r = 0; r < 4; ++r)
        Ls[wc][wr * 32 + m * 16 + g * 4 + r] = lrun[m][r];
  }
  __syncthreads();
  if (tid < 64) lbuf[(size_t)bh * S_ + tq * 64 + tid] = Ls[0][tid] + Ls[1][tid];
}

// --- attention pass 2: attn (f32, incl. zero upper-tri) + PV -> oh; K direct from L2 ---
__global__ __launch_bounds__(256, 4) void k_attn_out(const f16* __restrict__ qt,
    const f16* __restrict__ kt, const f16* __restrict__ vt,
    const float* __restrict__ lbuf, float* __restrict__ attn, f16* __restrict__ oh)
{
  __shared__ f16 Ps[64][136];
  const int tq = 31 - blockIdx.x;
  const int bh = blockIdx.y, b = bh >> 4, h = bh & 15;
  const int tid = threadIdx.x, lane = tid & 63, wid = tid >> 6;
  const int wr = wid >> 1, wc = wid & 1, g = lane >> 4, li = lane & 15;
  const int ntk = (tq + 2) >> 1;
  const f16* Qb = qt + (size_t)bh * S_ * HD_;
  const f16* Kb = kt + (size_t)bh * S_ * HD_;

  f16x8 qa[2][2];
#pragma unroll
  for (int m = 0; m < 2; ++m)
#pragma unroll
    for (int kk = 0; kk < 2; ++kk)
      qa[m][kk] = *(const f16x8*)&Qb[(size_t)(tq * 64 + wr * 32 + m * 16 + li) * HD_ + kk * 32 + g * 8];
  float il[2][4];
#pragma unroll
  for (int m = 0; m < 2; ++m)
#pragma unroll
    for (int r = 0; r < 4; ++r) {
      int row = tq * 64 + wr * 32 + m * 16 + g * 4 + r;
      il[m][r] = 1.f / lbuf[(size_t)bh * S_ + row];
    }

  f32x4 oacc[4];
#pragma unroll
  for (int n = 0; n < 4; ++n) oacc[n] = (f32x4){0.f, 0.f, 0.f, 0.f};

  const int r0 = tid >> 5, c0 = (tid & 31) * 4;

  for (int tk = 0; tk < 16; ++tk) {
    float* arow0 = attn + ((size_t)bh * S_ + tq * 64) * S_ + tk * 128;
    if (tk < ntk) {
      f16x8 kf[4][2];
#pragma unroll
      for (int n = 0; n < 4; ++n)
#pragma unroll
        for (int kk = 0; kk < 2; ++kk)
          kf[n][kk] = *(const f16x8*)&Kb[(size_t)(tk * 128 + wc * 64 + n * 16 + li) * HD_ + kk * 32 + g * 8];
      f32x4 acc[2][4];
#pragma unroll
      for (int m = 0; m < 2; ++m)
#pragma unroll
        for (int n = 0; n < 4; ++n) acc[m][n] = (f32x4){0.f, 0.f, 0.f, 0.f};
#pragma unroll
      for (int kk = 0; kk < 2; ++kk)
#pragma unroll
        for (int m = 0; m < 2; ++m)
#pragma unroll
          for (int n = 0; n < 4; ++n)
            acc[m][n] = __builtin_amdgcn_mfma_f32_16x16x32_f16(qa[m][kk], kf[n][kk], acc[m][n], 0, 0, 0);

      const bool diag = (tk == ntk - 1);
#pragma unroll
      for (int m = 0; m < 2; ++m)
#pragma unroll
        for (int r = 0; r < 4; ++r) {
          int row = tq * 64 + wr * 32 + m * 16 + g * 4 + r;
#pragma unroll
          for (int n = 0; n < 4; ++n) {
            float sv = acc[m][n][r] * SCALE;
            if (diag) { int col = tk * 128 + wc * 64 + n * 16 + li; if (col > row) sv = NEG_BIG; }
            float p = __expf(sv) * il[m][r];
            Ps[wr * 32 + m * 16 + g * 4 + r][wc * 64 + n * 16 + li] = (f16)p;
          }
        }
      __syncthreads();

      // coalesced attn write from LDS: 64 rows x 128 cols
      {
#pragma unroll
        for (int rr = 0; rr < 64; rr += 8) {
          int row = rr + r0;
          f16x4 hv = *(const f16x4*)&Ps[row][c0];
          f32x4 fv = {(float)hv[0], (float)hv[1], (float)hv[2], (float)hv[3]};
          *(f32x4*)(arow0 + (size_t)row * S_ + c0) = fv;
        }
      }

      // PV: wave wid owns rows wid*16..+15 of the 64-row out tile
#pragma unroll
      for (int kk = 0; kk < 4; ++kk) {
        f16x8 vbf[4];
#pragma unroll
        for (int n = 0; n < 4; ++n)
          vbf[n] = *(const f16x8*)&vt[((size_t)bh * HD_ + n * 16 + li) * S_ + tk * 128 + kk * 32 + g * 8];
        f16x8 pa = *(const f16x8*)&Ps[wid * 16 + li][kk * 32 + g * 8];
#pragma unroll
        for (int n = 0; n < 4; ++n)
          oacc[n] = __builtin_amdgcn_mfma_f32_16x16x32_f16(pa, vbf[n], oacc[n], 0, 0, 0);
      }
      __syncthreads();
    } else {
      // strictly-above-diagonal tile: attn = 0 (d_out is poisoned; must write)
      f32x4 z = {0.f, 0.f, 0.f, 0.f};
#pragma unroll
      for (int rr = 0; rr < 64; rr += 8)
        *(f32x4*)(arow0 + (size_t)(rr + r0) * S_ + c0) = z;
    }
  }

  // per-head output rows in [B,S,D] so proj GEMM consumes directly
#pragma unroll
  for (int n = 0; n < 4; ++n)
#pragma unroll
    for (int r = 0; r < 4; ++r) {
      int row = tq * 64 + wid * 16 + g * 4 + r;
      oh[(size_t)(b * S_ + row) * D_ + h * HD_ + n * 16 + li] = (f16)oacc[n][r];
    }
}

extern "C" void kernel_launch(void* const* d_in, const int* in_sizes, int n_in,
                              void* d_out, int out_size, void* d_ws, size_t ws_size,
                              hipStream_t stream)
{
  (void)in_sizes; (void)n_in; (void)out_size; (void)ws_size;
  const float* x  = (const float*)d_in[0];
  const float* Wq = (const float*)d_in[1];
  const float* Wk = (const float*)d_in[2];
  const float* Wv = (const float*)d_in[3];
  const float* Wp = (const float*)d_in[4];
  const float* bp = (const float*)d_in[5];
  const float* gq = (const float*)d_in[6];
  const float* bq = (const float*)d_in[7];
  const float* gk = (const float*)d_in[8];
  const float* bk = (const float*)d_in[9];

  float* out  = (float*)d_out;
  float* attn = out + (size_t)B_ * S_ * D_;

  f16* qt = (f16*)d_ws;                    // [B,H,S,HD]
  f16* kt = qt + (size_t)M_ * D_;          // [B,H,S,HD]
  f16* vh = kt + (size_t)M_ * D_;          // [B,H,S,HD]
  f16* vt = vh + (size_t)M_ * D_;          // [B,H,HD,S]
  f16* oh = vt + (size_t)M_ * D_;          // [B,S,D]
  float* lbuf = (float*)(oh + (size_t)M_ * D_);

  dim3 blk(256);
  k_gemm_qkv<<<dim3(32, 8, 3), blk, 0, stream>>>(x, Wq, Wk, Wv, gq, bq, gk, bk, qt, kt, vh);
  k_transpose_v<<<dim3(32, 16, 2), blk, 0, stream>>>(vh, vt);
  k_attn_stats<<<dim3(32, 32), blk, 0, stream>>>(qt, kt, lbuf);
  k_attn_out<<<dim3(32, 32), blk, 0, stream>>>(qt, kt, vt, lbuf, attn, oh);
  k_gemm_proj<<<dim3(32, 8), blk, 0, stream>>>(oh, Wp, bp, out);
}